// Round 1
// baseline (91.215 us; speedup 1.0000x reference)
//
#include <hip/hip_runtime.h>

// Problem dims (fixed by the reference)
#define BB 2
#define LL 1024
#define DI 1536
#define DS 16

// Chunked scan config
#define NCHUNK 8

// ---------------------------------------------------------------------------
// Pass 1: per (b, d, n, chunk) compute the chunk's affine summary (Aacc, Bacc)
// such that  x_after_chunk = Aacc * x_before_chunk + Bacc.
// Thread map: tid = dl*16 + n  (16 d-values x 16 n-states per 256-thread block)
// ---------------------------------------------------------------------------
template <int NC>
__global__ __launch_bounds__(256) void ss_pass1(
    const float* __restrict__ u, const float* __restrict__ delta,
    const float* __restrict__ A, const float* __restrict__ Bm,
    float2* __restrict__ summ)
{
    constexpr int CL = LL / NC;
    const int tid = threadIdx.x;
    const int n  = tid & 15;
    const int dl = tid >> 4;
    const int d  = blockIdx.x * 16 + dl;
    const int c  = blockIdx.y;
    const int b  = blockIdx.z;

    const float Aval = A[d * DS + n];

    const float* __restrict__ up = u     + (size_t)b * LL * DI + d;
    const float* __restrict__ dp = delta + (size_t)b * LL * DI + d;
    const float* __restrict__ bp = Bm    + (size_t)b * LL * DS + n;

    float Aacc = 1.0f;
    float Bacc = 0.0f;
    const int t0 = c * CL;
    for (int t = t0; t < t0 + CL; ++t) {
        const float dt = dp[(size_t)t * DI];
        const float uu = up[(size_t)t * DI];
        const float bb = bp[(size_t)t * DS];
        const float a  = __expf(dt * Aval);
        Aacc *= a;
        Bacc = fmaf(a, Bacc, dt * bb * uu);
    }
    summ[(((size_t)b * DI + d) * DS + n) * NC + c] = make_float2(Aacc, Bacc);
}

// ---------------------------------------------------------------------------
// Pass 2: fold predecessor-chunk summaries to get incoming state, re-run the
// chunk, reduce x*C over the 16 n-lanes (shfl_xor within the wave), write y.
// ---------------------------------------------------------------------------
template <int NC>
__global__ __launch_bounds__(256) void ss_pass2(
    const float* __restrict__ u, const float* __restrict__ delta,
    const float* __restrict__ A, const float* __restrict__ Bm,
    const float* __restrict__ Cm, const float* __restrict__ Dv,
    const float2* __restrict__ summ, float* __restrict__ y)
{
    constexpr int CL = LL / NC;
    const int tid = threadIdx.x;
    const int n  = tid & 15;
    const int dl = tid >> 4;
    const int d  = blockIdx.x * 16 + dl;
    const int c  = blockIdx.y;
    const int b  = blockIdx.z;

    const float Aval = A[d * DS + n];
    const float Dd   = Dv[d];

    const float* __restrict__ up = u     + (size_t)b * LL * DI + d;
    const float* __restrict__ dp = delta + (size_t)b * LL * DI + d;
    const float* __restrict__ bp = Bm    + (size_t)b * LL * DS + n;
    const float* __restrict__ cp = Cm    + (size_t)b * LL * DS + n;
    float* __restrict__ yp       = y     + (size_t)b * LL * DI + d;

    // Incoming state: fold chunks 0..c-1 (at most NC-1 = 7 tiny reads)
    float x = 0.0f;
    if (NC > 1) {
        const float2* __restrict__ sp = summ + (((size_t)b * DI + d) * DS + n) * NC;
        for (int cc = 0; cc < c; ++cc) {
            const float2 s = sp[cc];
            x = fmaf(s.x, x, s.y);
        }
    }

    const int t0 = c * CL;
    for (int t = t0; t < t0 + CL; ++t) {
        const float dt = dp[(size_t)t * DI];
        const float uu = up[(size_t)t * DI];
        const float bb = bp[(size_t)t * DS];
        const float cv = cp[(size_t)t * DS];
        const float a  = __expf(dt * Aval);
        x = fmaf(a, x, dt * bb * uu);

        float contrib = x * cv;
        // Reduce over the 16 n-lanes (lane = tid&63; n = lane&15, masks<16 stay in-group)
        contrib += __shfl_xor(contrib, 1);
        contrib += __shfl_xor(contrib, 2);
        contrib += __shfl_xor(contrib, 4);
        contrib += __shfl_xor(contrib, 8);

        if (n == 0) {
            yp[(size_t)t * DI] = fmaf(uu, Dd, contrib);
        }
    }
}

extern "C" void kernel_launch(void* const* d_in, const int* in_sizes, int n_in,
                              void* d_out, int out_size, void* d_ws, size_t ws_size,
                              hipStream_t stream) {
    const float* u     = (const float*)d_in[0];
    const float* delta = (const float*)d_in[1];
    const float* A     = (const float*)d_in[2];
    const float* Bm    = (const float*)d_in[3];
    const float* Cm    = (const float*)d_in[4];
    const float* Dv    = (const float*)d_in[5];
    float* y = (float*)d_out;

    const size_t summ_bytes = (size_t)BB * DI * DS * NCHUNK * sizeof(float2);

    if (ws_size >= summ_bytes) {
        float2* summ = (float2*)d_ws;
        dim3 grid(DI / 16, NCHUNK, BB);
        ss_pass1<NCHUNK><<<grid, 256, 0, stream>>>(u, delta, A, Bm, summ);
        ss_pass2<NCHUNK><<<grid, 256, 0, stream>>>(u, delta, A, Bm, Cm, Dv, summ, y);
    } else {
        // Fallback: unchunked single pass (no workspace needed)
        dim3 grid(DI / 16, 1, BB);
        ss_pass2<1><<<grid, 256, 0, stream>>>(u, delta, A, Bm, Cm, Dv, nullptr, y);
    }
}

// Round 2
// 54.737 us; speedup vs baseline: 1.6664x; 1.6664x over previous
//
#include <hip/hip_runtime.h>

// Problem dims (fixed by the reference)
#define BB 2
#define LL 1024
#define DI 1536
#define DS 16

// Chunking
#define NC 32
#define CL (LL / NC)   // 32
#define TPB 256

// ---------------------------------------------------------------------------
// Pass 1: thread <-> (b, d, chunk); all 16 n-states in registers.
// Computes per-chunk affine summary (Aacc_n, Bacc_n) for each n.
// summ layout: [c][b][d][n] (float2) -> coalesced writes & scan reads.
// ---------------------------------------------------------------------------
__global__ __launch_bounds__(TPB) void ss1(
    const float* __restrict__ u, const float* __restrict__ delta,
    const float* __restrict__ A, const float* __restrict__ Bm,
    float2* __restrict__ summ)
{
    const int d = blockIdx.x * TPB + threadIdx.x;   // consecutive threads -> consecutive d
    const int c = blockIdx.y;
    const int b = blockIdx.z;

    float Av[DS];
    #pragma unroll
    for (int n = 0; n < DS; ++n) Av[n] = A[d * DS + n];

    float Aacc[DS], Bacc[DS];
    #pragma unroll
    for (int n = 0; n < DS; ++n) { Aacc[n] = 1.0f; Bacc[n] = 0.0f; }

    const size_t bl0 = (size_t)b * LL + (size_t)c * CL;
    const float* __restrict__ dp = delta + bl0 * DI + d;
    const float* __restrict__ up = u     + bl0 * DI + d;
    const float* __restrict__ bp = Bm    + bl0 * DS;      // wave-uniform

    #pragma unroll 2
    for (int i = 0; i < CL; ++i) {
        const float dt = dp[(size_t)i * DI];   // coalesced 256B/wave
        const float uu = up[(size_t)i * DI];
        const float du = dt * uu;
        const float* __restrict__ bt = bp + i * DS;  // uniform -> s_load
        #pragma unroll
        for (int n = 0; n < DS; ++n) {
            const float a = __expf(dt * Av[n]);
            Aacc[n] *= a;
            Bacc[n] = fmaf(a, Bacc[n], du * bt[n]);
        }
    }

    float2* __restrict__ sp = summ + (((size_t)c * BB + b) * DI + d) * DS;
    #pragma unroll
    for (int n = 0; n < DS; ++n) sp[n] = make_float2(Aacc[n], Bacc[n]);
}

// ---------------------------------------------------------------------------
// Pass 1.5: exclusive scan of chunk summaries along c, per (b,d,n).
// gid = (b*DI+d)*DS+n; summ/xin stride between c-steps is BB*DI*DS.
// Coalesced: at fixed c, consecutive gid -> consecutive float2.
// ---------------------------------------------------------------------------
__global__ __launch_bounds__(TPB) void ss_scan(
    const float2* __restrict__ summ, float* __restrict__ xin)
{
    const int gid = blockIdx.x * TPB + threadIdx.x;
    const size_t cstride = (size_t)BB * DI * DS;
    float x = 0.0f;
    #pragma unroll 4
    for (int c = 0; c < NC; ++c) {
        xin[(size_t)c * cstride + gid] = x;     // state BEFORE chunk c
        const float2 s = summ[(size_t)c * cstride + gid];
        x = fmaf(s.x, x, s.y);
    }
}

// ---------------------------------------------------------------------------
// Pass 2: thread <-> (b, d, chunk); load incoming state, re-run chunk,
// reduce over n in registers, write y (coalesced).
// ---------------------------------------------------------------------------
template <int NCc>
__global__ __launch_bounds__(TPB) void ss2(
    const float* __restrict__ u, const float* __restrict__ delta,
    const float* __restrict__ A, const float* __restrict__ Bm,
    const float* __restrict__ Cm, const float* __restrict__ Dv,
    const float* __restrict__ xin, float* __restrict__ y)
{
    constexpr int CLL = LL / NCc;
    const int d = blockIdx.x * TPB + threadIdx.x;
    const int c = blockIdx.y;
    const int b = blockIdx.z;

    float Av[DS];
    #pragma unroll
    for (int n = 0; n < DS; ++n) Av[n] = A[d * DS + n];

    float x[DS];
    if (NCc > 1) {
        const float* __restrict__ xp = xin + (((size_t)c * BB + b) * DI + d) * DS;
        #pragma unroll
        for (int n = 0; n < DS; ++n) x[n] = xp[n];
    } else {
        #pragma unroll
        for (int n = 0; n < DS; ++n) x[n] = 0.0f;
    }

    const float Dd = Dv[d];

    const size_t bl0 = (size_t)b * LL + (size_t)c * CLL;
    const float* __restrict__ dp = delta + bl0 * DI + d;
    const float* __restrict__ up = u     + bl0 * DI + d;
    const float* __restrict__ bp = Bm    + bl0 * DS;   // uniform
    const float* __restrict__ cp = Cm    + bl0 * DS;   // uniform
    float* __restrict__ yp       = y     + bl0 * DI + d;

    #pragma unroll 2
    for (int i = 0; i < CLL; ++i) {
        const float dt = dp[(size_t)i * DI];
        const float uu = up[(size_t)i * DI];
        const float du = dt * uu;
        const float* __restrict__ bt = bp + i * DS;
        const float* __restrict__ ct = cp + i * DS;
        float y0 = 0.0f, y1 = 0.0f;
        #pragma unroll
        for (int n = 0; n < DS; ++n) {
            const float a = __expf(dt * Av[n]);
            x[n] = fmaf(a, x[n], du * bt[n]);
            if (n & 1) y1 = fmaf(x[n], ct[n], y1);
            else       y0 = fmaf(x[n], ct[n], y0);
        }
        yp[(size_t)i * DI] = fmaf(uu, Dd, y0 + y1);
    }
}

extern "C" void kernel_launch(void* const* d_in, const int* in_sizes, int n_in,
                              void* d_out, int out_size, void* d_ws, size_t ws_size,
                              hipStream_t stream) {
    const float* u     = (const float*)d_in[0];
    const float* delta = (const float*)d_in[1];
    const float* A     = (const float*)d_in[2];
    const float* Bm    = (const float*)d_in[3];
    const float* Cm    = (const float*)d_in[4];
    const float* Dv    = (const float*)d_in[5];
    float* y = (float*)d_out;

    const size_t summ_elems = (size_t)NC * BB * DI * DS;         // float2 each
    const size_t summ_bytes = summ_elems * sizeof(float2);       // 12.58 MB
    const size_t xin_bytes  = summ_elems * sizeof(float);        // 6.29 MB

    if (ws_size >= summ_bytes + xin_bytes) {
        float2* summ = (float2*)d_ws;
        float*  xin  = (float*)((char*)d_ws + summ_bytes);

        dim3 grid1(DI / TPB, NC, BB);
        ss1<<<grid1, TPB, 0, stream>>>(u, delta, A, Bm, summ);

        dim3 gridS((BB * DI * DS) / TPB, 1, 1);
        ss_scan<<<gridS, TPB, 0, stream>>>(summ, xin);

        ss2<NC><<<grid1, TPB, 0, stream>>>(u, delta, A, Bm, Cm, Dv, xin, y);
    } else {
        // Fallback: single-chunk serial scan (slow but correct, no workspace)
        dim3 grid(DI / TPB, 1, BB);
        ss2<1><<<grid, TPB, 0, stream>>>(u, delta, A, Bm, Cm, Dv, nullptr, y);
    }
}

// Round 3
// 49.254 us; speedup vs baseline: 1.8519x; 1.1113x over previous
//
#include <hip/hip_runtime.h>

// Problem dims (fixed by the reference)
#define BB 2
#define LL 1024
#define DI 1536
#define DS 16

// Chunking
#define NC 64
#define CL (LL / NC)   // 16
#define TPB 256

#define LOG2E 1.44269504088896340736f

__device__ __forceinline__ float exp2_fast(float x) { return __builtin_amdgcn_exp2f(x); }

// ---------------------------------------------------------------------------
// Pass 1: thread <-> (b, d, chunk); all 16 n-states in registers.
// Stores per-chunk: sdt = sum(delta) (decay summary, n-independent) and
// Bacc[n] (folded input term):  x_after = exp2(Av2[n]*sdt)*x_before + Bacc[n]
// Layouts: sdt [c][b][d], bsum [c][b][d][n]  (coalesced everywhere)
// ---------------------------------------------------------------------------
__global__ __launch_bounds__(TPB) void ss1(
    const float* __restrict__ u, const float* __restrict__ delta,
    const float* __restrict__ A, const float* __restrict__ Bm,
    float* __restrict__ sdt_out, float* __restrict__ bsum)
{
    const int d = blockIdx.x * TPB + threadIdx.x;   // consecutive threads -> consecutive d
    const int c = blockIdx.y;
    const int b = blockIdx.z;

    float Av2[DS];
    #pragma unroll
    for (int n = 0; n < DS; ++n) Av2[n] = A[d * DS + n] * LOG2E;

    const size_t bl0 = (size_t)b * LL + (size_t)c * CL;
    const float* __restrict__ dp = delta + bl0 * DI + d;
    const float* __restrict__ up = u     + bl0 * DI + d;
    const float* __restrict__ bp = Bm    + bl0 * DS;      // wave-uniform -> s_load

    // Upfront burst loads: 32 independent global_load_dword, pipelined
    float dt[CL], uu[CL];
    #pragma unroll
    for (int i = 0; i < CL; ++i) {
        dt[i] = dp[(size_t)i * DI];
        uu[i] = up[(size_t)i * DI];
    }

    float Bacc[DS];
    #pragma unroll
    for (int n = 0; n < DS; ++n) Bacc[n] = 0.0f;
    float sdt = 0.0f;

    #pragma unroll
    for (int i = 0; i < CL; ++i) {
        const float du = dt[i] * uu[i];
        sdt += dt[i];
        const float* __restrict__ bt = bp + i * DS;
        #pragma unroll
        for (int n = 0; n < DS; ++n) {
            const float a = exp2_fast(dt[i] * Av2[n]);
            Bacc[n] = fmaf(a, Bacc[n], du * bt[n]);
        }
    }

    sdt_out[((size_t)c * BB + b) * DI + d] = sdt;
    float* __restrict__ sp = bsum + (((size_t)c * BB + b) * DI + d) * DS;
    #pragma unroll
    for (int n = 0; n < DS; ++n) sp[n] = Bacc[n];
}

// ---------------------------------------------------------------------------
// Pass 1.5: exclusive scan over chunks per (b,d,n).
// gid = (b*DI+d)*DS+n. Chunk decay rebuilt as exp2(Av2 * sdt[c]).
// ---------------------------------------------------------------------------
__global__ __launch_bounds__(TPB) void ss_scan(
    const float* __restrict__ A,
    const float* __restrict__ sdt_in, const float* __restrict__ bsum,
    float* __restrict__ xin)
{
    const int gid = blockIdx.x * TPB + threadIdx.x;
    const int bd  = gid >> 4;          // b*DI + d
    const int d   = bd % DI;
    const int n   = gid & 15;
    const float Av2 = A[d * DS + n] * LOG2E;

    const size_t cstr = (size_t)BB * DI * DS;
    const size_t sstr = (size_t)BB * DI;

    float x = 0.0f;
    #pragma unroll 4
    for (int c = 0; c < NC; ++c) {
        xin[(size_t)c * cstr + gid] = x;      // state BEFORE chunk c
        const float a = exp2_fast(Av2 * sdt_in[(size_t)c * sstr + bd]);
        x = fmaf(a, x, bsum[(size_t)c * cstr + gid]);
    }
}

// ---------------------------------------------------------------------------
// Pass 2: thread <-> (b, d, chunk); load incoming state, re-run chunk,
// reduce over n in registers, write y (coalesced).
// ---------------------------------------------------------------------------
__global__ __launch_bounds__(TPB) void ss2(
    const float* __restrict__ u, const float* __restrict__ delta,
    const float* __restrict__ A, const float* __restrict__ Bm,
    const float* __restrict__ Cm, const float* __restrict__ Dv,
    const float* __restrict__ xin, float* __restrict__ y)
{
    const int d = blockIdx.x * TPB + threadIdx.x;
    const int c = blockIdx.y;
    const int b = blockIdx.z;

    float Av2[DS];
    #pragma unroll
    for (int n = 0; n < DS; ++n) Av2[n] = A[d * DS + n] * LOG2E;

    float x[DS];
    const float* __restrict__ xp = xin + (((size_t)c * BB + b) * DI + d) * DS;
    #pragma unroll
    for (int n = 0; n < DS; ++n) x[n] = xp[n];

    const float Dd = Dv[d];

    const size_t bl0 = (size_t)b * LL + (size_t)c * CL;
    const float* __restrict__ dp = delta + bl0 * DI + d;
    const float* __restrict__ up = u     + bl0 * DI + d;
    const float* __restrict__ bp = Bm    + bl0 * DS;   // uniform
    const float* __restrict__ cp = Cm    + bl0 * DS;   // uniform
    float* __restrict__ yp       = y     + bl0 * DI + d;

    float dt[CL], uu[CL];
    #pragma unroll
    for (int i = 0; i < CL; ++i) {
        dt[i] = dp[(size_t)i * DI];
        uu[i] = up[(size_t)i * DI];
    }

    #pragma unroll
    for (int i = 0; i < CL; ++i) {
        const float du = dt[i] * uu[i];
        const float* __restrict__ bt = bp + i * DS;
        const float* __restrict__ ct = cp + i * DS;
        float y0 = 0.0f, y1 = 0.0f;
        #pragma unroll
        for (int n = 0; n < DS; ++n) {
            const float a = exp2_fast(dt[i] * Av2[n]);
            x[n] = fmaf(a, x[n], du * bt[n]);
            if (n & 1) y1 = fmaf(x[n], ct[n], y1);
            else       y0 = fmaf(x[n], ct[n], y0);
        }
        yp[(size_t)i * DI] = fmaf(uu[i], Dd, y0 + y1);
    }
}

// Fallback: streaming single-chunk serial scan (no workspace needed)
__global__ __launch_bounds__(TPB) void ss_serial(
    const float* __restrict__ u, const float* __restrict__ delta,
    const float* __restrict__ A, const float* __restrict__ Bm,
    const float* __restrict__ Cm, const float* __restrict__ Dv,
    float* __restrict__ y)
{
    const int d = blockIdx.x * TPB + threadIdx.x;
    const int b = blockIdx.z;

    float Av2[DS];
    #pragma unroll
    for (int n = 0; n < DS; ++n) Av2[n] = A[d * DS + n] * LOG2E;

    float x[DS];
    #pragma unroll
    for (int n = 0; n < DS; ++n) x[n] = 0.0f;

    const float Dd = Dv[d];
    const size_t bl0 = (size_t)b * LL;
    const float* __restrict__ dp = delta + bl0 * DI + d;
    const float* __restrict__ up = u     + bl0 * DI + d;
    const float* __restrict__ bp = Bm    + bl0 * DS;
    const float* __restrict__ cp = Cm    + bl0 * DS;
    float* __restrict__ yp       = y     + bl0 * DI + d;

    for (int t = 0; t < LL; ++t) {
        const float dt = dp[(size_t)t * DI];
        const float uu = up[(size_t)t * DI];
        const float du = dt * uu;
        const float* __restrict__ bt = bp + t * DS;
        const float* __restrict__ ct = cp + t * DS;
        float y0 = 0.0f, y1 = 0.0f;
        #pragma unroll
        for (int n = 0; n < DS; ++n) {
            const float a = exp2_fast(dt * Av2[n]);
            x[n] = fmaf(a, x[n], du * bt[n]);
            if (n & 1) y1 = fmaf(x[n], ct[n], y1);
            else       y0 = fmaf(x[n], ct[n], y0);
        }
        yp[(size_t)t * DI] = fmaf(uu, Dd, y0 + y1);
    }
}

extern "C" void kernel_launch(void* const* d_in, const int* in_sizes, int n_in,
                              void* d_out, int out_size, void* d_ws, size_t ws_size,
                              hipStream_t stream) {
    const float* u     = (const float*)d_in[0];
    const float* delta = (const float*)d_in[1];
    const float* A     = (const float*)d_in[2];
    const float* Bm    = (const float*)d_in[3];
    const float* Cm    = (const float*)d_in[4];
    const float* Dv    = (const float*)d_in[5];
    float* y = (float*)d_out;

    const size_t sdt_bytes  = (size_t)NC * BB * DI * sizeof(float);            // 0.79 MB
    const size_t bsum_bytes = (size_t)NC * BB * DI * DS * sizeof(float);       // 12.6 MB
    const size_t xin_bytes  = bsum_bytes;                                      // 12.6 MB

    if (ws_size >= sdt_bytes + bsum_bytes + xin_bytes) {
        float* sdt  = (float*)d_ws;
        float* bsum = (float*)((char*)d_ws + sdt_bytes);
        float* xin  = (float*)((char*)d_ws + sdt_bytes + bsum_bytes);

        dim3 grid1(DI / TPB, NC, BB);
        ss1<<<grid1, TPB, 0, stream>>>(u, delta, A, Bm, sdt, bsum);

        dim3 gridS((BB * DI * DS) / TPB, 1, 1);
        ss_scan<<<gridS, TPB, 0, stream>>>(A, sdt, bsum, xin);

        ss2<<<grid1, TPB, 0, stream>>>(u, delta, A, Bm, Cm, Dv, xin, y);
    } else {
        dim3 grid(DI / TPB, 1, BB);
        ss_serial<<<grid, TPB, 0, stream>>>(u, delta, A, Bm, Cm, Dv, y);
    }
}